// Round 1
// baseline (1267.113 us; speedup 1.0000x reference)
//
#include <hip/hip_runtime.h>
#include <stdint.h>

#define S_LEN 2048
#define HS_DIM 1024
#define NHEAD 16
#define HD_DIM 64
#define NBATCH 2

typedef __attribute__((ext_vector_type(8))) short short8;
typedef __attribute__((ext_vector_type(4))) float floatx4;

__device__ __forceinline__ unsigned short f2bf(float f) {
  unsigned int u = __float_as_uint(f);
  u += 0x7fffu + ((u >> 16) & 1u);   // RTN
  return (unsigned short)(u >> 16);
}

__device__ __forceinline__ floatx4 mfma_bf16(short8 a, short8 b, floatx4 c) {
  return __builtin_amdgcn_mfma_f32_16x16x32_bf16(a, b, c, 0, 0, 0);
}

__device__ __forceinline__ float bfly_max16(float v) {
  v = fmaxf(v, __shfl_xor(v, 1, 64));
  v = fmaxf(v, __shfl_xor(v, 2, 64));
  v = fmaxf(v, __shfl_xor(v, 4, 64));
  v = fmaxf(v, __shfl_xor(v, 8, 64));
  return v;
}
__device__ __forceinline__ float bfly_sum16(float v) {
  v += __shfl_xor(v, 1, 64);
  v += __shfl_xor(v, 2, 64);
  v += __shfl_xor(v, 4, 64);
  v += __shfl_xor(v, 8, 64);
  return v;
}

// async global->LDS, 16B per lane; LDS dst = wave-uniform base + lane*16
__device__ __forceinline__ void gload_lds16(const unsigned short* g, unsigned short* l) {
  __builtin_amdgcn_global_load_lds(
      (const __attribute__((address_space(1))) unsigned int*)(const void*)g,
      (__attribute__((address_space(3))) unsigned int*)(void*)l, 16, 0, 0);
}

// ---------------------------------------------------------------- mask pack
__global__ __launch_bounds__(256) void pack_mask_k(const int* __restrict__ mask,
                                                   unsigned long long* __restrict__ mp) {
  int idx = blockIdx.x * 256 + threadIdx.x;
  int v = mask[idx];
  unsigned long long bal = __ballot(v != 0);
  if ((threadIdx.x & 63) == 0) mp[idx >> 6] = bal;
}

// ---------------------------------------------------------------- query column sums
// grid 128 = (B=2) x (64 row-chunks of 32)
__global__ __launch_bounds__(256) void qsum_k(const float* __restrict__ q,
                                              float* __restrict__ qsum) {
  int b = blockIdx.x >> 6, rc = blockIdx.x & 63;
  int tid = threadIdx.x;
  float a0 = 0.f, a1 = 0.f, a2 = 0.f, a3 = 0.f;
  const float* base = q + ((size_t)b * S_LEN + rc * 32) * HS_DIM;
  for (int r = 0; r < 32; r++) {
    const float* row = base + (size_t)r * HS_DIM;
    a0 += row[tid];       a1 += row[tid + 256];
    a2 += row[tid + 512]; a3 += row[tid + 768];
  }
  atomicAdd(&qsum[b * HS_DIM + tid], a0);
  atomicAdd(&qsum[b * HS_DIM + tid + 256], a1);
  atomicAdd(&qsum[b * HS_DIM + tid + 512], a2);
  atomicAdd(&qsum[b * HS_DIM + tid + 768], a3);
}

// ---------------------------------------------------------------- h = relu(mean(q) @ Wp1 + bp1)
__global__ __launch_bounds__(256) void mlp_h_k(const float* __restrict__ qsum,
                                               const float* __restrict__ Wp1,
                                               const float* __restrict__ bp1,
                                               float* __restrict__ hbuf) {
  __shared__ float red[4][64];
  int b = blockIdx.x >> 3;
  int j0 = (blockIdx.x & 7) * 64;
  int tid = threadIdx.x;
  int j = j0 + (tid & 63), seg = tid >> 6;
  float partial = 0.f;
  for (int i = seg * 256; i < seg * 256 + 256; i++)
    partial += qsum[b * HS_DIM + i] * Wp1[(size_t)i * 512 + j];
  red[seg][tid & 63] = partial;
  __syncthreads();
  if (seg == 0) {
    float s = red[0][tid] + red[1][tid] + red[2][tid] + red[3][tid];
    s = s * (1.0f / 2048.0f) + bp1[j];
    hbuf[b * 512 + j] = fmaxf(s, 0.f);
  }
}

// ---------------------------------------------------------------- pattern softmax + per-(b,h) scale
__global__ __launch_bounds__(256) void patsel_k(const float* __restrict__ hbuf,
                                                const float* __restrict__ Wp2,
                                                const float* __restrict__ bp2,
                                                const float* __restrict__ patterns,
                                                float* __restrict__ patout) {
  __shared__ float logits[16];
  __shared__ float pw[2][8];
  int tid = threadIdx.x;
  int g = tid >> 4, t = tid & 15;
  int b = g >> 3, p = g & 7;
  float partial = 0.f;
  for (int i = t; i < 512; i += 16) partial += hbuf[b * 512 + i] * Wp2[i * 8 + p];
  partial += __shfl_xor(partial, 1, 64);
  partial += __shfl_xor(partial, 2, 64);
  partial += __shfl_xor(partial, 4, 64);
  partial += __shfl_xor(partial, 8, 64);
  if (t == 0) logits[g] = partial + bp2[p];
  __syncthreads();
  if (tid < 2) {
    float mx = -INFINITY;
    for (int i = 0; i < 8; i++) mx = fmaxf(mx, logits[tid * 8 + i]);
    float s = 0.f;
    for (int i = 0; i < 8; i++) { float e = __expf(logits[tid * 8 + i] - mx); pw[tid][i] = e; s += e; }
    float inv = 1.f / s;
    for (int i = 0; i < 8; i++) pw[tid][i] *= inv;
  }
  __syncthreads();
  if (tid < 32) {
    int b2 = tid >> 4, hh = tid & 15;
    float acc = 0.f;
    for (int i = 0; i < 8; i++) acc += pw[b2][i] * patterns[i * 16 + hh];
    patout[b2 * 16 + hh] = acc;
  }
}

// ---------------------------------------------------------------- f32 -> bf16 convert (8 elems/thread)
__global__ __launch_bounds__(256) void conv_bf16_k(const float* __restrict__ in,
                                                   unsigned short* __restrict__ out) {
  size_t idx = (size_t)blockIdx.x * 256 + threadIdx.x;
  const float4* p = (const float4*)in + idx * 2;
  float4 a = p[0], b = p[1];
  uint4 r;
  r.x = (unsigned)f2bf(a.x) | ((unsigned)f2bf(a.y) << 16);
  r.y = (unsigned)f2bf(a.z) | ((unsigned)f2bf(a.w) << 16);
  r.z = (unsigned)f2bf(b.x) | ((unsigned)f2bf(b.y) << 16);
  r.w = (unsigned)f2bf(b.z) | ((unsigned)f2bf(b.w) << 16);
  ((uint4*)out)[idx] = r;
}

// ---------------------------------------------------------------- W [k][n] f32 -> Wt [n][k] bf16
// grid (16,16,4): 64x64 tiles, z selects matrix
__global__ __launch_bounds__(256) void transpose_wt_k(
    const float* __restrict__ W0, const float* __restrict__ W1,
    const float* __restrict__ W2, const float* __restrict__ W3,
    unsigned short* __restrict__ T0, unsigned short* __restrict__ T1,
    unsigned short* __restrict__ T2, unsigned short* __restrict__ T3) {
  const float* W = (blockIdx.z == 0) ? W0 : (blockIdx.z == 1) ? W1 : (blockIdx.z == 2) ? W2 : W3;
  unsigned short* Wt = (blockIdx.z == 0) ? T0 : (blockIdx.z == 1) ? T1 : (blockIdx.z == 2) ? T2 : T3;
  __shared__ unsigned short T[64][78];
  int tid = threadIdx.x;
  int r = tid >> 2, c0 = (tid & 3) * 16;
  int k0 = blockIdx.x * 64, n0 = blockIdx.y * 64;
  const float* src = W + (size_t)(k0 + r) * HS_DIM + n0 + c0;
#pragma unroll
  for (int q4 = 0; q4 < 4; q4++) {
    float4 v = ((const float4*)src)[q4];
    T[c0 + q4 * 4 + 0][r] = f2bf(v.x);
    T[c0 + q4 * 4 + 1][r] = f2bf(v.y);
    T[c0 + q4 * 4 + 2][r] = f2bf(v.z);
    T[c0 + q4 * 4 + 3][r] = f2bf(v.w);
  }
  __syncthreads();
  unsigned short* d = Wt + (size_t)(n0 + r) * HS_DIM + k0 + c0;
  unsigned int pk[8];
#pragma unroll
  for (int i = 0; i < 8; i++)
    pk[i] = (unsigned)T[r][c0 + 2 * i] | ((unsigned)T[r][c0 + 2 * i + 1] << 16);
  uint4 o0, o1;
  o0.x = pk[0]; o0.y = pk[1]; o0.z = pk[2]; o0.w = pk[3];
  o1.x = pk[4]; o1.y = pk[5]; o1.z = pk[6]; o1.w = pk[7];
  ((uint4*)d)[0] = o0;
  ((uint4*)d)[1] = o1;
}

// ---------------------------------------------------------------- bf16 GEMM: out = A[4096,1024] @ Bt^T + bias
// A row-major [m][k] bf16, Bt row-major [n][k] bf16 (pre-transposed W).
// 512 threads = 8 waves (2m x 4n), BM=BN=128, BK=32, global_load_lds staging (m97 structure).
// OUT_MODE 0: bf16 into [b][h][s][d]; OUT_MODE 1: f32 [m][n].
template <int OUT_MODE>
__global__ __launch_bounds__(512, 2) void gemm_bf(const unsigned short* __restrict__ A,
                                                  const unsigned short* __restrict__ Bt,
                                                  const float* __restrict__ bias,
                                                  void* __restrict__ dst) {
  __shared__ __align__(16) unsigned short Al[128 * 32];
  __shared__ __align__(16) unsigned short Bl[128 * 32];
  const int tid = threadIdx.x;
  const int w = tid >> 6, lane = tid & 63, quad = lane >> 4, l16 = lane & 15;
  const int wm = w >> 2, wn = w & 3;
  const int m0 = blockIdx.x * 128, n0 = blockIdx.y * 128;

  // staging: 8KB tile / 512 threads = one 16B gload_lds per thread per tile
  const int r_s = tid >> 2, kb_s = (tid & 3) * 8;
  const unsigned short* Ag = A + (size_t)(m0 + r_s) * HS_DIM + kb_s;
  const unsigned short* Bg = Bt + (size_t)(n0 + r_s) * HS_DIM + kb_s;
  unsigned short* Al_b = &Al[w * 512];   // wave-uniform LDS base
  unsigned short* Bl_b = &Bl[w * 512];

  floatx4 cd[4][2];
#pragma unroll
  for (int mi = 0; mi < 4; mi++)
#pragma unroll
    for (int ni = 0; ni < 2; ni++) cd[mi][ni] = (floatx4){0.f, 0.f, 0.f, 0.f};

  for (int kt = 0; kt < HS_DIM; kt += 32) {
    __syncthreads();                 // WAR: prior reads done before overwrite
    gload_lds16(Ag + kt, Al_b);
    gload_lds16(Bg + kt, Bl_b);
    __syncthreads();                 // drains vmcnt -> tiles ready
    short8 af[4], bf2[2];
#pragma unroll
    for (int mi = 0; mi < 4; mi++)
      af[mi] = *(const short8*)&Al[(wm * 64 + mi * 16 + l16) * 32 + quad * 8];
#pragma unroll
    for (int ni = 0; ni < 2; ni++)
      bf2[ni] = *(const short8*)&Bl[(wn * 32 + ni * 16 + l16) * 32 + quad * 8];
#pragma unroll
    for (int mi = 0; mi < 4; mi++)
#pragma unroll
      for (int ni = 0; ni < 2; ni++) cd[mi][ni] = mfma_bf16(af[mi], bf2[ni], cd[mi][ni]);
  }

#pragma unroll
  for (int ni = 0; ni < 2; ni++) {
    int n = n0 + wn * 32 + ni * 16 + l16;
    float bv = bias[n];
#pragma unroll
    for (int mi = 0; mi < 4; mi++)
#pragma unroll
      for (int jj = 0; jj < 4; jj++) {
        int m = m0 + wm * 64 + mi * 16 + quad * 4 + jj;
        float val = cd[mi][ni][jj] + bv;
        if (OUT_MODE == 0) {
          int bb = m >> 11, s = m & 2047, hh = n >> 6, d = n & 63;
          ((unsigned short*)dst)[(((size_t)(bb * NHEAD + hh)) * S_LEN + s) * HD_DIM + d] = f2bf(val);
        } else {
          ((float*)dst)[(size_t)m * HS_DIM + n] = val;
        }
      }
  }
}

// ---------------------------------------------------------------- fused attention v2
// grid (32,32) -> XCD-chunked (bh, q-block). Phase 1: stats, zero LDS/barriers, K frags
// direct from global (L2). Phase 2: 128-col tiles; Vt double-buffered + XOR-swizzled
// (conflict-free transpose); weights stored nontemporal straight from registers; wl bf16
// swizzled feeds PV A-frags. ctx written bf16. LDS 48KB -> 3 blocks/CU.
__global__ __launch_bounds__(256, 3) void attn_fused(const unsigned short* __restrict__ Q,
                                                     const unsigned short* __restrict__ K,
                                                     const unsigned short* __restrict__ V,
                                                     const unsigned long long* __restrict__ mpack,
                                                     const float* __restrict__ pat,
                                                     float* __restrict__ attn_out,
                                                     unsigned short* __restrict__ ctx) {
  __shared__ __align__(16) unsigned short Vt[2][64][128];  // [buf][d][k'] swizzled V^T
  __shared__ __align__(16) unsigned short wl[4][16][128];  // per-wave P tile, bf16, swizzled

  const int tid = threadIdx.x;
  const int w = tid >> 6, lane = tid & 63, quad = lane >> 4, l16 = lane & 15;
  // bijective XCD chunk swizzle: 4 heads' K/V (2MB) per XCD L2
  const int lin = blockIdx.x + (blockIdx.y << 5);
  const int nid = ((lin & 7) << 7) + (lin >> 3);
  const int bh = nid >> 5;
  const int q0 = (nid & 31) << 6;
  const int b = bh >> 4, h = bh & 15;

  const unsigned short* Qb = Q + ((size_t)bh * S_LEN + q0) * HD_DIM;
  const unsigned short* Kb = K + (size_t)bh * S_LEN * HD_DIM;
  const unsigned short* Vb = V + (size_t)bh * S_LEN * HD_DIM;
  const float scl = 0.125f * pat[bh];

  // Q fragments direct from global (A-frag: row=l16, k=quad*8)
  const int qrow_w = w * 16 + l16;
  const short8 aq0 = *(const short8*)(Qb + qrow_w * HD_DIM + quad * 8);
  const short8 aq1 = *(const short8*)(Qb + qrow_w * HD_DIM + 32 + quad * 8);

  const int qrow_base = q0 + w * 16 + quad * 4;
  const unsigned long long* mrow = mpack + ((size_t)b * S_LEN + qrow_base) * 32;

  float m_i[4], l_i[4];
#pragma unroll
  for (int jj = 0; jj < 4; jj++) { m_i[jj] = -INFINITY; l_i[jj] = 0.f; }

  // ---------------- phase 1: per-row max & sum(exp); K direct from global ----------------
  short8 kc0[4], kc1[4];
#pragma unroll
  for (int nt = 0; nt < 4; nt++) {
    const unsigned short* kr = Kb + (nt * 16 + l16) * HD_DIM;
    kc0[nt] = *(const short8*)(kr + quad * 8);
    kc1[nt] = *(const short8*)(kr + 32 + quad * 8);
  }
  for (int jt = 0; jt < 32; ++jt) {
    short8 kn0[4], kn1[4];
    if (jt < 31) {
      const unsigned short* Kt = Kb + (size_t)(jt + 1) * 64 * HD_DIM;
#pragma unroll
      for (int nt = 0; nt < 4; nt++) {
        const unsigned short* kr = Kt + (nt * 16 + l16) * HD_DIM;
        kn0[nt] = *(const short8*)(kr + quad * 8);
        kn1[nt] = *(const short8*)(kr + 32 + quad * 8);
      }
    }
    floatx4 c[4];
#pragma unroll
    for (int nt = 0; nt < 4; nt++) {
      floatx4 acc = (floatx4){0.f, 0.f, 0.f, 0.f};
      acc = mfma_bf16(aq0, kc0[nt], acc);
      acc = mfma_bf16(aq1, kc1[nt], acc);
      c[nt] = acc;
    }
#pragma unroll
    for (int jj = 0; jj < 4; jj++) {
      unsigned long long pk = mrow[jj * 32 + jt];
      float sv[4], tmax = -INFINITY;
#pragma unroll
      for (int nt = 0; nt < 4; nt++) {
        int col = nt * 16 + l16;
        float s = ((pk >> col) & 1ull) ? c[nt][jj] * scl : -1e9f;
        sv[nt] = s; tmax = fmaxf(tmax, s);
      }
      tmax = bfly_max16(tmax);
      float newm = fmaxf(m_i[jj], tmax);
      float ps = 0.f;
#pragma unroll
      for (int nt = 0; nt < 4; nt++) ps += __expf(sv[nt] - newm);
      ps = bfly_sum16(ps);
      l_i[jj] = l_i[jj] * __expf(m_i[jj] - newm) + ps;
      m_i[jj] = newm;
    }
    if (jt < 31) {
#pragma unroll
      for (int nt = 0; nt < 4; nt++) { kc0[nt] = kn0[nt]; kc1[nt] = kn1[nt]; }
    }
  }
  float inv_l[4];
#pragma unroll
  for (int jj = 0; jj < 4; jj++) inv_l[jj] = 1.f / l_i[jj];

  // ---------------- phase 2: weights out + PV ----------------
  floatx4 o[4];
#pragma unroll
  for (int dt = 0; dt < 4; dt++) o[dt] = (floatx4){0.f, 0.f, 0.f, 0.f};
  const int kw = (l16 & 7) ^ (l16 >> 3);    // wl read swizzle key (row = l16)
  const int vr_r = tid >> 3;                // V staging: r = p*32 + vr_r
  const int vr_c8 = (tid & 7) * 8;

  // prologue: stage V tile 0 into Vt[0]
#pragma unroll
  for (int p = 0; p < 4; p++) {
    int r = p * 32 + vr_r;
    union { uint4 v; unsigned short u[8]; } U;
    U.v = *(const uint4*)(Vb + (size_t)r * HD_DIM + vr_c8);
#pragma unroll
    for (int i = 0; i < 8; i++) {
      int d = vr_c8 + i;
      int kv = (d & 7) ^ (d >> 3);
      Vt[0][d][(((r >> 3) ^ kv) << 3) + (r & 7)] = U.u[i];
    }
  }
  __syncthreads();

  float* arow = attn_out + (size_t)bh * S_LEN * S_LEN;
  for (int j = 0; j < 16; ++j) {
    const int buf = j & 1;
    // T14 issue-early: next V tile into registers
    uint4 vreg[4];
    if (j < 15) {
#pragma unroll
      for (int p = 0; p < 4; p++) {
        int r = p * 32 + vr_r;
        vreg[p] = *(const uint4*)(Vb + (size_t)((j + 1) * 128 + r) * HD_DIM + vr_c8);
      }
    }
    const unsigned short* Kt = Kb + (size_t)j * 128 * HD_DIM;
    unsigned long long pk0[4], pk1[4];
#pragma unroll
    for (int jj = 0; jj < 4; jj++) {
      pk0[jj] = mrow[jj * 32 + j * 2];
      pk1[jj] = mrow[jj * 32 + j * 2 + 1];
    }
    // QK^T (K direct from L2) + softmax finish + weight store + wl write, streamed per nt
#pragma unroll
    for (int nt = 0; nt < 8; nt++) {
      const unsigned short* kr = Kt + (nt * 16 + l16) * HD_DIM;
      floatx4 acc = (floatx4){0.f, 0.f, 0.f, 0.f};
      acc = mfma_bf16(aq0, *(const short8*)(kr + quad * 8), acc);
      acc = mfma_bf16(aq1, *(const short8*)(kr + 32 + quad * 8), acc);
      const int col = nt * 16 + l16;
      const int u = col >> 3;
#pragma unroll
      for (int jj = 0; jj < 4; jj++) {
        unsigned long long bits = (nt < 4) ? pk0[jj] : pk1[jj];
        float s = ((bits >> (col & 63)) & 1ull) ? acc[jj] * scl : -1e9f;
        float wv = __expf(s - m_i[jj]) * inv_l[jj];
        // direct f32 store: quad-grouped lanes -> 4 fully-used 64B segments / instr
        __builtin_nontemporal_store(wv, arow + (size_t)(qrow_base + jj) * S_LEN + j * 128 + col);
        int row = quad * 4 + jj;
        int keyw = (row & 7) ^ (row >> 3);
        wl[w][row][((u ^ keyw) << 3) + (l16 & 7)] = f2bf(wv);
      }
    }
    // PV: A from wl (bf16, swizzled), B from Vt[buf] (swizzled V^T); wave-private DS order
#pragma unroll
    for (int kk = 0; kk < 4; kk++) {
      short8 pa = *(const short8*)&wl[w][l16][((kk * 4 + quad) ^ kw) << 3];
#pragma unroll
      for (int dt = 0; dt < 4; dt++) {
        int d = dt * 16 + l16;
        int kv = (d & 7) ^ (d >> 3);
        o[dt] = mfma_bf16(pa, *(const short8*)&Vt[buf][d][((kk * 4 + quad) ^ kv) << 3], o[dt]);
      }
    }
    // T14 write-late: transpose-store next V tile into Vt[buf^1] (conflict-free via swizzle)
    if (j < 15) {
#pragma unroll
      for (int p = 0; p < 4; p++) {
        int r = p * 32 + vr_r;
        union { uint4 v; unsigned short u[8]; } U;
        U.v = vreg[p];
#pragma unroll
        for (int i = 0; i < 8; i++) {
          int d = vr_c8 + i;
          int kv = (d & 7) ^ (d >> 3);
          Vt[buf ^ 1][d][(((r >> 3) ^ kv) << 3) + (r & 7)] = U.u[i];
        }
      }
    }
    __syncthreads();   // single barrier per tile: protects Vt[buf] reuse + buf^1 publish
  }

  // ctx bf16 [b][s][h*64+d]
#pragma unroll
  for (int dt = 0; dt < 4; dt++)
#pragma unroll
    for (int jj = 0; jj < 4; jj++)
      ctx[((size_t)b * S_LEN + qrow_base + jj) * HS_DIM + h * HD_DIM + dt * 16 + l16] =
          f2bf(o[dt][jj]);
}

// ---------------------------------------------------------------- launch
extern "C" void kernel_launch(void* const* d_in, const int* in_sizes, int n_in,
                              void* d_out, int out_size, void* d_ws, size_t ws_size,
                              hipStream_t stream) {
  const float* query = (const float*)d_in[0];
  const float* key   = (const float*)d_in[1];
  const float* value = (const float*)d_in[2];
  const int*   amask = (const int*)d_in[3];
  const float* Wq = (const float*)d_in[4];
  const float* bq = (const float*)d_in[5];
  const float* Wk = (const float*)d_in[6];
  const float* bk = (const float*)d_in[7];
  const float* Wv = (const float*)d_in[8];
  const float* bv = (const float*)d_in[9];
  const float* Wo = (const float*)d_in[10];
  const float* bo = (const float*)d_in[11];
  const float* Wp1 = (const float*)d_in[12];
  const float* bp1 = (const float*)d_in[13];
  const float* Wp2 = (const float*)d_in[14];
  const float* bp2 = (const float*)d_in[15];
  const float* patterns = (const float*)d_in[16];

  float* out = (float*)d_out;                           // [2,2048,1024] f32
  float* attn = out + (size_t)NBATCH * S_LEN * HS_DIM;  // [2,16,2048,2048] f32

  char* ws = (char*)d_ws;
  unsigned short* cb  = (unsigned short*)(ws + 0);         // 8 MiB convert buf, later ctx bf16
  unsigned short* Wqt = (unsigned short*)(ws + 8388608);   // 2 MiB each
  unsigned short* Wkt = (unsigned short*)(ws + 10485760);
  unsigned short* Wvt = (unsigned short*)(ws + 12582912);
  unsigned short* Wot = (unsigned short*)(ws + 14680064);
  unsigned short* Qw  = (unsigned short*)(ws + 16777216);  // 8 MiB each
  unsigned short* Kw  = (unsigned short*)(ws + 25165824);
  unsigned short* Vw  = (unsigned short*)(ws + 33554432);
  unsigned long long* mpack = (unsigned long long*)(ws + 41943040);  // 1 MiB
  float* qsum = (float*)(ws + 42991616);                   // 8 KiB
  float* hbuf = (float*)(ws + 42999808);                   // 4 KiB
  float* patb = (float*)(ws + 43003904);                   // 128 B

  hipMemsetAsync(qsum, 0, 8192, stream);

  pack_mask_k<<<dim3(32768), dim3(256), 0, stream>>>(amask, mpack);
  qsum_k<<<dim3(128), dim3(256), 0, stream>>>(query, qsum);
  mlp_h_k<<<dim3(16), dim3(256), 0, stream>>>(qsum, Wp1, bp1, hbuf);
  patsel_k<<<dim3(1), dim3(256), 0, stream>>>(hbuf, Wp2, bp2, patterns, patb);

  transpose_wt_k<<<dim3(16, 16, 4), dim3(256), 0, stream>>>(Wq, Wk, Wv, Wo,
                                                            Wqt, Wkt, Wvt, Wot);

  conv_bf16_k<<<dim3(2048), dim3(256), 0, stream>>>(query, cb);
  gemm_bf<0><<<dim3(32, 8), dim3(512), 0, stream>>>(cb, Wqt, bq, (void*)Qw);
  conv_bf16_k<<<dim3(2048), dim3(256), 0, stream>>>(key, cb);
  gemm_bf<0><<<dim3(32, 8), dim3(512), 0, stream>>>(cb, Wkt, bk, (void*)Kw);
  conv_bf16_k<<<dim3(2048), dim3(256), 0, stream>>>(value, cb);
  gemm_bf<0><<<dim3(32, 8), dim3(512), 0, stream>>>(cb, Wvt, bv, (void*)Vw);

  attn_fused<<<dim3(32, 32), dim3(256), 0, stream>>>(Qw, Kw, Vw, mpack, patb, attn, cb);

  gemm_bf<1><<<dim3(32, 8), dim3(512), 0, stream>>>(cb, Wot, bo, (void*)out);
}

// Round 3
// 911.466 us; speedup vs baseline: 1.3902x; 1.3902x over previous
//
#include <hip/hip_runtime.h>
#include <stdint.h>

#define S_LEN 2048
#define HS_DIM 1024
#define NHEAD 16
#define HD_DIM 64
#define NBATCH 2

typedef __attribute__((ext_vector_type(8))) short short8;
typedef __attribute__((ext_vector_type(4))) float floatx4;

__device__ __forceinline__ unsigned short f2bf(float f) {
  unsigned int u = __float_as_uint(f);
  u += 0x7fffu + ((u >> 16) & 1u);   // RTN
  return (unsigned short)(u >> 16);
}

__device__ __forceinline__ floatx4 mfma_bf16(short8 a, short8 b, floatx4 c) {
  return __builtin_amdgcn_mfma_f32_16x16x32_bf16(a, b, c, 0, 0, 0);
}

__device__ __forceinline__ float bfly_max16(float v) {
  v = fmaxf(v, __shfl_xor(v, 1, 64));
  v = fmaxf(v, __shfl_xor(v, 2, 64));
  v = fmaxf(v, __shfl_xor(v, 4, 64));
  v = fmaxf(v, __shfl_xor(v, 8, 64));
  return v;
}
__device__ __forceinline__ float bfly_sum16(float v) {
  v += __shfl_xor(v, 1, 64);
  v += __shfl_xor(v, 2, 64);
  v += __shfl_xor(v, 4, 64);
  v += __shfl_xor(v, 8, 64);
  return v;
}

// async global->LDS, 16B per lane. g must be PER-LANE (lane i reads g[i*8..i*8+7]);
// LDS dst = wave-uniform base + lane*16.
__device__ __forceinline__ void gload_lds16(const unsigned short* g, unsigned short* l) {
  __builtin_amdgcn_global_load_lds(
      (const __attribute__((address_space(1))) unsigned int*)(const void*)g,
      (__attribute__((address_space(3))) unsigned int*)(void*)l, 16, 0, 0);
}

// ---------------------------------------------------------------- mask pack
__global__ __launch_bounds__(256) void pack_mask_k(const int* __restrict__ mask,
                                                   unsigned long long* __restrict__ mp) {
  int idx = blockIdx.x * 256 + threadIdx.x;
  int v = mask[idx];
  unsigned long long bal = __ballot(v != 0);
  if ((threadIdx.x & 63) == 0) mp[idx >> 6] = bal;
}

// ---------------------------------------------------------------- query column sums
__global__ __launch_bounds__(256) void qsum_k(const float* __restrict__ q,
                                              float* __restrict__ qsum) {
  int b = blockIdx.x >> 6, rc = blockIdx.x & 63;
  int tid = threadIdx.x;
  float a0 = 0.f, a1 = 0.f, a2 = 0.f, a3 = 0.f;
  const float* base = q + ((size_t)b * S_LEN + rc * 32) * HS_DIM;
  for (int r = 0; r < 32; r++) {
    const float* row = base + (size_t)r * HS_DIM;
    a0 += row[tid];       a1 += row[tid + 256];
    a2 += row[tid + 512]; a3 += row[tid + 768];
  }
  atomicAdd(&qsum[b * HS_DIM + tid], a0);
  atomicAdd(&qsum[b * HS_DIM + tid + 256], a1);
  atomicAdd(&qsum[b * HS_DIM + tid + 512], a2);
  atomicAdd(&qsum[b * HS_DIM + tid + 768], a3);
}

// ---------------------------------------------------------------- h = relu(mean(q) @ Wp1 + bp1)
__global__ __launch_bounds__(256) void mlp_h_k(const float* __restrict__ qsum,
                                               const float* __restrict__ Wp1,
                                               const float* __restrict__ bp1,
                                               float* __restrict__ hbuf) {
  __shared__ float red[4][64];
  int b = blockIdx.x >> 3;
  int j0 = (blockIdx.x & 7) * 64;
  int tid = threadIdx.x;
  int j = j0 + (tid & 63), seg = tid >> 6;
  float partial = 0.f;
  for (int i = seg * 256; i < seg * 256 + 256; i++)
    partial += qsum[b * HS_DIM + i] * Wp1[(size_t)i * 512 + j];
  red[seg][tid & 63] = partial;
  __syncthreads();
  if (seg == 0) {
    float s = red[0][tid] + red[1][tid] + red[2][tid] + red[3][tid];
    s = s * (1.0f / 2048.0f) + bp1[j];
    hbuf[b * 512 + j] = fmaxf(s, 0.f);
  }
}

// ---------------------------------------------------------------- pattern softmax + per-(b,h) scale
__global__ __launch_bounds__(256) void patsel_k(const float* __restrict__ hbuf,
                                                const float* __restrict__ Wp2,
                                                const float* __restrict__ bp2,
                                                const float* __restrict__ patterns,
                                                float* __restrict__ patout) {
  __shared__ float logits[16];
  __shared__ float pw[2][8];
  int tid = threadIdx.x;
  int g = tid >> 4, t = tid & 15;
  int b = g >> 3, p = g & 7;
  float partial = 0.f;
  for (int i = t; i < 512; i += 16) partial += hbuf[b * 512 + i] * Wp2[i * 8 + p];
  partial += __shfl_xor(partial, 1, 64);
  partial += __shfl_xor(partial, 2, 64);
  partial += __shfl_xor(partial, 4, 64);
  partial += __shfl_xor(partial, 8, 64);
  if (t == 0) logits[g] = partial + bp2[p];
  __syncthreads();
  if (tid < 2) {
    float mx = -INFINITY;
    for (int i = 0; i < 8; i++) mx = fmaxf(mx, logits[tid * 8 + i]);
    float s = 0.f;
    for (int i = 0; i < 8; i++) { float e = __expf(logits[tid * 8 + i] - mx); pw[tid][i] = e; s += e; }
    float inv = 1.f / s;
    for (int i = 0; i < 8; i++) pw[tid][i] *= inv;
  }
  __syncthreads();
  if (tid < 32) {
    int b2 = tid >> 4, hh = tid & 15;
    float acc = 0.f;
    for (int i = 0; i < 8; i++) acc += pw[b2][i] * patterns[i * 16 + hh];
    patout[b2 * 16 + hh] = acc;
  }
}

// ---------------------------------------------------------------- f32 -> bf16 convert (8 elems/thread)
__global__ __launch_bounds__(256) void conv_bf16_k(const float* __restrict__ in,
                                                   unsigned short* __restrict__ out) {
  size_t idx = (size_t)blockIdx.x * 256 + threadIdx.x;
  const float4* p = (const float4*)in + idx * 2;
  float4 a = p[0], b = p[1];
  uint4 r;
  r.x = (unsigned)f2bf(a.x) | ((unsigned)f2bf(a.y) << 16);
  r.y = (unsigned)f2bf(a.z) | ((unsigned)f2bf(a.w) << 16);
  r.z = (unsigned)f2bf(b.x) | ((unsigned)f2bf(b.y) << 16);
  r.w = (unsigned)f2bf(b.z) | ((unsigned)f2bf(b.w) << 16);
  ((uint4*)out)[idx] = r;
}

// ---------------------------------------------------------------- W [k][n] f32 -> Wt [n][k] bf16
__global__ __launch_bounds__(256) void transpose_wt_k(
    const float* __restrict__ W0, const float* __restrict__ W1,
    const float* __restrict__ W2, const float* __restrict__ W3,
    unsigned short* __restrict__ T0, unsigned short* __restrict__ T1,
    unsigned short* __restrict__ T2, unsigned short* __restrict__ T3) {
  const float* W = (blockIdx.z == 0) ? W0 : (blockIdx.z == 1) ? W1 : (blockIdx.z == 2) ? W2 : W3;
  unsigned short* Wt = (blockIdx.z == 0) ? T0 : (blockIdx.z == 1) ? T1 : (blockIdx.z == 2) ? T2 : T3;
  __shared__ unsigned short T[64][78];
  int tid = threadIdx.x;
  int r = tid >> 2, c0 = (tid & 3) * 16;
  int k0 = blockIdx.x * 64, n0 = blockIdx.y * 64;
  const float* src = W + (size_t)(k0 + r) * HS_DIM + n0 + c0;
#pragma unroll
  for (int q4 = 0; q4 < 4; q4++) {
    float4 v = ((const float4*)src)[q4];
    T[c0 + q4 * 4 + 0][r] = f2bf(v.x);
    T[c0 + q4 * 4 + 1][r] = f2bf(v.y);
    T[c0 + q4 * 4 + 2][r] = f2bf(v.z);
    T[c0 + q4 * 4 + 3][r] = f2bf(v.w);
  }
  __syncthreads();
  unsigned short* d = Wt + (size_t)(n0 + r) * HS_DIM + k0 + c0;
  unsigned int pk[8];
#pragma unroll
  for (int i = 0; i < 8; i++)
    pk[i] = (unsigned)T[r][c0 + 2 * i] | ((unsigned)T[r][c0 + 2 * i + 1] << 16);
  uint4 o0, o1;
  o0.x = pk[0]; o0.y = pk[1]; o0.z = pk[2]; o0.w = pk[3];
  o1.x = pk[4]; o1.y = pk[5]; o1.z = pk[6]; o1.w = pk[7];
  ((uint4*)d)[0] = o0;
  ((uint4*)d)[1] = o1;
}

// ---------------------------------------------------------------- bf16 GEMM: out = A[4096,1024] @ Bt^T + bias
// OUT_MODE 0: bf16 into [b][h][s][d] with 16B-chunk XOR swizzle (chunk' = chunk ^ (s&7));
// OUT_MODE 1: f32 [m][n].
template <int OUT_MODE>
__global__ __launch_bounds__(512, 2) void gemm_bf(const unsigned short* __restrict__ A,
                                                  const unsigned short* __restrict__ Bt,
                                                  const float* __restrict__ bias,
                                                  void* __restrict__ dst) {
  __shared__ __align__(16) unsigned short Al[128 * 32];
  __shared__ __align__(16) unsigned short Bl[128 * 32];
  const int tid = threadIdx.x;
  const int w = tid >> 6, lane = tid & 63, quad = lane >> 4, l16 = lane & 15;
  const int wm = w >> 2, wn = w & 3;
  const int m0 = blockIdx.x * 128, n0 = blockIdx.y * 128;

  const int r_s = tid >> 2, kb_s = (tid & 3) * 8;
  const unsigned short* Ag = A + (size_t)(m0 + r_s) * HS_DIM + kb_s;
  const unsigned short* Bg = Bt + (size_t)(n0 + r_s) * HS_DIM + kb_s;
  unsigned short* Al_b = &Al[w * 512];
  unsigned short* Bl_b = &Bl[w * 512];

  floatx4 cd[4][2];
#pragma unroll
  for (int mi = 0; mi < 4; mi++)
#pragma unroll
    for (int ni = 0; ni < 2; ni++) cd[mi][ni] = (floatx4){0.f, 0.f, 0.f, 0.f};

  for (int kt = 0; kt < HS_DIM; kt += 32) {
    __syncthreads();
    gload_lds16(Ag + kt, Al_b);
    gload_lds16(Bg + kt, Bl_b);
    __syncthreads();
    short8 af[4], bf2[2];
#pragma unroll
    for (int mi = 0; mi < 4; mi++)
      af[mi] = *(const short8*)&Al[(wm * 64 + mi * 16 + l16) * 32 + quad * 8];
#pragma unroll
    for (int ni = 0; ni < 2; ni++)
      bf2[ni] = *(const short8*)&Bl[(wn * 32 + ni * 16 + l16) * 32 + quad * 8];
#pragma unroll
    for (int mi = 0; mi < 4; mi++)
#pragma unroll
      for (int ni = 0; ni < 2; ni++) cd[mi][ni] = mfma_bf16(af[mi], bf2[ni], cd[mi][ni]);
  }

#pragma unroll
  for (int ni = 0; ni < 2; ni++) {
    int n = n0 + wn * 32 + ni * 16 + l16;
    float bv = bias[n];
#pragma unroll
    for (int mi = 0; mi < 4; mi++)
#pragma unroll
      for (int jj = 0; jj < 4; jj++) {
        int m = m0 + wm * 64 + mi * 16 + quad * 4 + jj;
        float val = cd[mi][ni][jj] + bv;
        if (OUT_MODE == 0) {
          int bb = m >> 11, s = m & 2047, hh = n >> 6, d = n & 63;
          int sd = (((d >> 3) ^ (s & 7)) << 3) | (d & 7);   // 16B-chunk swizzle
          ((unsigned short*)dst)[(((size_t)(bb * NHEAD + hh)) * S_LEN + s) * HD_DIM + sd] = f2bf(val);
        } else {
          ((float*)dst)[(size_t)m * HS_DIM + n] = val;
        }
      }
  }
}

// ---------------------------------------------------------------- fused attention v3.1
// Q/K/V in global are 16B-chunk XOR-swizzled (chunk' = chunk ^ (row&7)) so that
// global_load_lds (linear dest, PER-LANE source) + unpadded LDS tiles give conflict-free
// ds_read_b128. Phase 1: 128-row K tiles, LDS dbuf, 1 barrier/tile. Phase 2: 64-col
// tiles, K dbuf via gload_lds + Vt dbuf via T14 reg staging, f32 wl -> full-line stores.
__global__ __launch_bounds__(256, 3) void attn_fused(const unsigned short* __restrict__ Q,
                                                     const unsigned short* __restrict__ K,
                                                     const unsigned short* __restrict__ V,
                                                     const unsigned long long* __restrict__ mpack,
                                                     const float* __restrict__ pat,
                                                     float* __restrict__ attn_out,
                                                     unsigned short* __restrict__ ctx) {
  struct P1 { unsigned short Kl[2][128][64]; };                       // 32 KiB
  struct P2 {
    unsigned short Kl[2][64][64];                                     // 16 KiB
    unsigned short Vt[2][64][64];                                     // 16 KiB [buf][d][k'] swizzled V^T
    float wl[4][16][68];                                              // 17 KiB per-wave P tile
  };
  union SMemU { P1 p1; P2 p2; };
  __shared__ __align__(16) SMemU sm;

  const int tid = threadIdx.x;
  const int w = tid >> 6, lane = tid & 63, quad = lane >> 4, l16 = lane & 15;
  // bijective XCD chunk swizzle: 4 heads' K/V per XCD L2
  const int lin = blockIdx.x + (blockIdx.y << 5);
  const int nid = ((lin & 7) << 7) + (lin >> 3);
  const int bh = nid >> 5;
  const int q0 = (nid & 31) << 6;
  const int b = bh >> 4, h = bh & 15;

  const unsigned short* Qb = Q + ((size_t)bh * S_LEN + q0) * HD_DIM;
  const unsigned short* Kb = K + (size_t)bh * S_LEN * HD_DIM;
  const unsigned short* Vb = V + (size_t)bh * S_LEN * HD_DIM;
  const float scl = 0.125f * pat[bh];

  // fragment chunk offsets under the global swizzle (frag rows have row&7 == l16&7)
  const int key_q = l16 & 7;
  const int cs0 = (quad ^ key_q) << 3;          // k 0..31
  const int cs1 = ((quad + 4) ^ key_q) << 3;    // k 32..63

  const int qrow_w = w * 16 + l16;
  const short8 aq0 = *(const short8*)(Qb + (size_t)qrow_w * HD_DIM + cs0);
  const short8 aq1 = *(const short8*)(Qb + (size_t)qrow_w * HD_DIM + cs1);

  const int qrow_base = q0 + w * 16 + quad * 4;
  const unsigned long long* mrow = mpack + ((size_t)b * S_LEN + qrow_base) * 32;

  float m_i[4], l_i[4];
#pragma unroll
  for (int jj = 0; jj < 4; jj++) { m_i[jj] = -INFINITY; l_i[jj] = 0.f; }

  // per-lane source offset for linear 1KiB wave copies (8 contiguous 128B rows)
  const int lofs = lane * 8;   // shorts

  auto stage_k1 = [&](int jt, int buf) {
    const unsigned short* kg = Kb + ((size_t)jt * 128 + w * 32) * HD_DIM + lofs;
#pragma unroll
    for (int t = 0; t < 4; t++)
      gload_lds16(kg + t * 8 * HD_DIM, &sm.p1.Kl[buf][w * 32 + t * 8][0]);
  };

  // ---------------- phase 1: per-row max & sum(exp) ----------------
  stage_k1(0, 0);
  __syncthreads();
  for (int jt = 0; jt < 16; ++jt) {
    const int buf = jt & 1;
    if (jt < 15) stage_k1(jt + 1, buf ^ 1);
    floatx4 c[8];
#pragma unroll
    for (int nt = 0; nt < 8; nt++) {
      const unsigned short* kr = &sm.p1.Kl[buf][nt * 16 + l16][0];
      floatx4 acc = (floatx4){0.f, 0.f, 0.f, 0.f};
      acc = mfma_bf16(aq0, *(const short8*)(kr + cs0), acc);
      acc = mfma_bf16(aq1, *(const short8*)(kr + cs1), acc);
      c[nt] = acc;
    }
#pragma unroll
    for (int jj = 0; jj < 4; jj++) {
      unsigned long long pk0 = mrow[jj * 32 + jt * 2];
      unsigned long long pk1 = mrow[jj * 32 + jt * 2 + 1];
      float sv[8], tmax = -INFINITY;
#pragma unroll
      for (int nt = 0; nt < 8; nt++) {
        int col = nt * 16 + l16;
        unsigned long long bits = (nt < 4) ? pk0 : pk1;
        float s = ((bits >> (col & 63)) & 1ull) ? c[nt][jj] * scl : -1e9f;
        sv[nt] = s; tmax = fmaxf(tmax, s);
      }
      tmax = bfly_max16(tmax);
      float newm = fmaxf(m_i[jj], tmax);
      float ps = 0.f;
#pragma unroll
      for (int nt = 0; nt < 8; nt++) ps += __expf(sv[nt] - newm);
      ps = bfly_sum16(ps);
      l_i[jj] = l_i[jj] * __expf(m_i[jj] - newm) + ps;
      m_i[jj] = newm;
    }
    __syncthreads();
  }
  float inv_l[4];
#pragma unroll
  for (int jj = 0; jj < 4; jj++) inv_l[jj] = 1.f / l_i[jj];

  // ---------------- phase 2: weights out + PV ----------------
  floatx4 o[4];
#pragma unroll
  for (int dt = 0; dt < 4; dt++) o[dt] = (floatx4){0.f, 0.f, 0.f, 0.f};

  const int vrow = tid >> 2;     // tile kpos 0..63
  const int vc = tid & 3;        // stored-chunk pair (vc, vc+4)
  const int kr7 = vrow & 7, krh = vrow >> 3;
  uint4 vreg0, vreg1;

  auto stage_k2 = [&](int j, int buf) {
    const unsigned short* kg = Kb + ((size_t)j * 64 + w * 16) * HD_DIM + lofs;
    gload_lds16(kg, &sm.p2.Kl[buf][w * 16][0]);
    gload_lds16(kg + 8 * HD_DIM, &sm.p2.Kl[buf][w * 16 + 8][0]);
  };
  auto load_v = [&](int j) {
    const unsigned short* vg = Vb + ((size_t)j * 64 + vrow) * HD_DIM;
    vreg0 = *(const uint4*)(vg + vc * 8);
    vreg1 = *(const uint4*)(vg + (vc + 4) * 8);
  };
  auto scatter_v = [&](int buf) {
    union U8 { uint4 v; unsigned short u[8]; } U0, U1;
    U0.v = vreg0; U1.v = vreg1;
    const int dc0 = vc ^ kr7, dc1 = (vc + 4) ^ kr7;    // actual d-chunks
#pragma unroll
    for (int i = 0; i < 8; i++) {
      int kd0 = i ^ dc0;                                // key(d) = (d&7)^(d>>3)
      sm.p2.Vt[buf][(dc0 << 3) + i][((krh ^ kd0) << 3) + kr7] = U0.u[i];
      int kd1 = i ^ dc1;
      sm.p2.Vt[buf][(dc1 << 3) + i][((krh ^ kd1) << 3) + kr7] = U1.u[i];
    }
  };

  stage_k2(0, 0);
  load_v(0);
  scatter_v(0);
  __syncthreads();

  float* arow = attn_out + (size_t)bh * S_LEN * S_LEN + (size_t)q0 * S_LEN;
  for (int j = 0; j < 32; ++j) {
    const int buf = j & 1;
    // T14 issue-early: next K tile (gload_lds) + next V tile (regs)
    if (j < 31) { stage_k2(j + 1, buf ^ 1); load_v(j + 1); }

    unsigned long long pk[4];
#pragma unroll
    for (int jj = 0; jj < 4; jj++) pk[jj] = mrow[jj * 32 + j];

    // QK^T from Kl[buf] + softmax finish -> wl (f32)
#pragma unroll
    for (int nt = 0; nt < 4; nt++) {
      const unsigned short* kr = &sm.p2.Kl[buf][nt * 16 + l16][0];
      floatx4 acc = (floatx4){0.f, 0.f, 0.f, 0.f};
      acc = mfma_bf16(aq0, *(const short8*)(kr + cs0), acc);
      acc = mfma_bf16(aq1, *(const short8*)(kr + cs1), acc);
      const int col = nt * 16 + l16;
#pragma unroll
      for (int jj = 0; jj < 4; jj++) {
        float s = ((pk[jj] >> col) & 1ull) ? acc[jj] * scl : -1e9f;
        sm.p2.wl[w][quad * 4 + jj][col] = __expf(s - m_i[jj]) * inv_l[jj];
      }
    }

    // weight store: 256B contiguous per row segment (full 128B lines)
#pragma unroll
    for (int p = 0; p < 4; p++) {
      int r = p * 4 + quad;
      *(float4*)(arow + (size_t)(w * 16 + r) * S_LEN + j * 64 + l16 * 4) =
          *(const float4*)&sm.p2.wl[w][r][l16 * 4];
    }

    // PV: A from wl (f32 -> bf16), B from Vt[buf]
#pragma unroll
    for (int ks = 0; ks < 2; ks++) {
      float4 wa0 = *(const float4*)&sm.p2.wl[w][l16][ks * 32 + quad * 8];
      float4 wa1 = *(const float4*)&sm.p2.wl[w][l16][ks * 32 + quad * 8 + 4];
      short8 pa;
      pa[0] = (short)f2bf(wa0.x); pa[1] = (short)f2bf(wa0.y);
      pa[2] = (short)f2bf(wa0.z); pa[3] = (short)f2bf(wa0.w);
      pa[4] = (short)f2bf(wa1.x); pa[5] = (short)f2bf(wa1.y);
      pa[6] = (short)f2bf(wa1.z); pa[7] = (short)f2bf(wa1.w);
#pragma unroll
      for (int dt = 0; dt < 4; dt++) {
        int d = dt * 16 + l16;
        int kd = (d & 7) ^ (d >> 3);
        o[dt] = mfma_bf16(pa, *(const short8*)&sm.p2.Vt[buf][d][((ks * 4 + quad) ^ kd) << 3],
                          o[dt]);
      }
    }

    // T14 write-late: publish next V tile
    if (j < 31) scatter_v(buf ^ 1);
    __syncthreads();
  }

  // ctx bf16 [b][s][h*64+d] (standard layout for the output GEMM)
#pragma unroll
  for (int dt = 0; dt < 4; dt++)
#pragma unroll
    for (int jj = 0; jj < 4; jj++)
      ctx[((size_t)b * S_LEN + qrow_base + jj) * HS_DIM + h * HD_DIM + dt * 16 + l16] =
          f2bf(o[dt][jj]);
}

// ---------------------------------------------------------------- launch
extern "C" void kernel_launch(void* const* d_in, const int* in_sizes, int n_in,
                              void* d_out, int out_size, void* d_ws, size_t ws_size,
                              hipStream_t stream) {
  const float* query = (const float*)d_in[0];
  const float* key   = (const float*)d_in[1];
  const float* value = (const float*)d_in[2];
  const int*   amask = (const int*)d_in[3];
  const float* Wq = (const float*)d_in[4];
  const float* bq = (const float*)d_in[5];
  const float* Wk = (const float*)d_in[6];
  const float* bk = (const float*)d_in[7];
  const float* Wv = (const float*)d_in[8];
  const float* bv = (const float*)d_in[9];
  const float* Wo = (const float*)d_in[10];
  const float* bo = (const float*)d_in[11];
  const float* Wp1 = (const float*)d_in[12];
  const float* bp1 = (const float*)d_in[13];
  const float* Wp2 = (const float*)d_in[14];
  const float* bp2 = (const float*)d_in[15];
  const float* patterns = (const float*)d_in[16];

  float* out = (float*)d_out;                           // [2,2048,1024] f32
  float* attn = out + (size_t)NBATCH * S_LEN * HS_DIM;  // [2,16,2048,2048] f32

  char* ws = (char*)d_ws;
  unsigned short* cb  = (unsigned short*)(ws + 0);         // 8 MiB convert buf, later ctx bf16
  unsigned short* Wqt = (unsigned short*)(ws + 8388608);   // 2 MiB each
  unsigned short* Wkt = (unsigned short*)(ws + 10485760);
  unsigned short* Wvt = (unsigned short*)(ws + 12582912);
  unsigned short* Wot = (unsigned short*)(ws + 14680064);
  unsigned short* Qw  = (unsigned short*)(ws + 16777216);  // 8 MiB each (swizzled)
  unsigned short* Kw  = (unsigned short*)(ws + 25165824);
  unsigned short* Vw  = (unsigned short*)(ws + 33554432);
  unsigned long long* mpack = (unsigned long long*)(ws + 41943040);  // 1 MiB
  float* qsum = (float*)(ws + 42991616);                   // 8 KiB
  float* hbuf = (float*)(ws + 42999808);                   // 4 KiB
  float* patb = (float*)(ws + 43003904);                   // 128 B

  hipMemsetAsync(qsum, 0, 8192, stream);

  pack_mask_k<<<dim3(32768), dim3(256), 0, stream>>>(amask, mpack);
  qsum_k<<<dim3(128), dim3(256), 0, stream>>>(query, qsum);
  mlp_h_k<<<dim3(16), dim3(256), 0, stream>>>(qsum, Wp1, bp1, hbuf);
  patsel_k<<<dim3(1), dim3(256), 0, stream>>>(hbuf, Wp2, bp2, patterns, patb);

  transpose_wt_k<<<dim3(16, 16, 4), dim3(256), 0, stream>>>(Wq, Wk, Wv, Wo,
                                                            Wqt, Wkt, Wvt, Wot);

  conv_bf16_k<<<dim3(2048), dim3(256), 0, stream>>>(query, cb);
  gemm_bf<0><<<dim3(32, 8), dim3(512), 0, stream>>>(cb, Wqt, bq, (void*)Qw);
  conv_bf16_k<<<dim3(2048), dim3(256), 0, stream>>>(key, cb);
  gemm_bf<0><<<dim3(32, 8), dim3(512), 0, stream>>>(cb, Wkt, bk, (void*)Kw);
  conv_bf16_k<<<dim3(2048), dim3(256), 0, stream>>>(value, cb);
  gemm_bf<0><<<dim3(32, 8), dim3(512), 0, stream>>>(cb, Wvt, bv, (void*)Vw);

  attn_fused<<<dim3(32, 32), dim3(256), 0, stream>>>(Qw, Kw, Vw, mpack, patb, attn, cb);

  gemm_bf<1><<<dim3(32, 8), dim3(512), 0, stream>>>(cb, Wot, bo, (void*)out);
}

// Round 4
// 821.418 us; speedup vs baseline: 1.5426x; 1.1096x over previous
//
#include <hip/hip_runtime.h>
#include <stdint.h>

#define S_LEN 2048
#define HS_DIM 1024
#define NHEAD 16
#define HD_DIM 64
#define NBATCH 2

typedef __attribute__((ext_vector_type(8))) short short8;
typedef __attribute__((ext_vector_type(4))) float floatx4;

__device__ __forceinline__ unsigned short f2bf(float f) {
  unsigned int u = __float_as_uint(f);
  u += 0x7fffu + ((u >> 16) & 1u);   // RTN
  return (unsigned short)(u >> 16);
}

__device__ __forceinline__ floatx4 mfma_bf16(short8 a, short8 b, floatx4 c) {
  return __builtin_amdgcn_mfma_f32_16x16x32_bf16(a, b, c, 0, 0, 0);
}

__device__ __forceinline__ float bfly_max16(float v) {
  v = fmaxf(v, __shfl_xor(v, 1, 64));
  v = fmaxf(v, __shfl_xor(v, 2, 64));
  v = fmaxf(v, __shfl_xor(v, 4, 64));
  v = fmaxf(v, __shfl_xor(v, 8, 64));
  return v;
}
__device__ __forceinline__ float bfly_sum16(float v) {
  v += __shfl_xor(v, 1, 64);
  v += __shfl_xor(v, 2, 64);
  v += __shfl_xor(v, 4, 64);
  v += __shfl_xor(v, 8, 64);
  return v;
}

// async global->LDS, 16B per lane. g must be PER-LANE (lane i reads g[i*8..i*8+7]);
// LDS dst = wave-uniform base + lane*16.
__device__ __forceinline__ void gload_lds16(const unsigned short* g, unsigned short* l) {
  __builtin_amdgcn_global_load_lds(
      (const __attribute__((address_space(1))) unsigned int*)(const void*)g,
      (__attribute__((address_space(3))) unsigned int*)(void*)l, 16, 0, 0);
}

// ---------------------------------------------------------------- mask pack
__global__ __launch_bounds__(256) void pack_mask_k(const int* __restrict__ mask,
                                                   unsigned long long* __restrict__ mp) {
  int idx = blockIdx.x * 256 + threadIdx.x;
  int v = mask[idx];
  unsigned long long bal = __ballot(v != 0);
  if ((threadIdx.x & 63) == 0) mp[idx >> 6] = bal;
}

// ---------------------------------------------------------------- query column sums
__global__ __launch_bounds__(256) void qsum_k(const float* __restrict__ q,
                                              float* __restrict__ qsum) {
  int b = blockIdx.x >> 6, rc = blockIdx.x & 63;
  int tid = threadIdx.x;
  float a0 = 0.f, a1 = 0.f, a2 = 0.f, a3 = 0.f;
  const float* base = q + ((size_t)b * S_LEN + rc * 32) * HS_DIM;
  for (int r = 0; r < 32; r++) {
    const float* row = base + (size_t)r * HS_DIM;
    a0 += row[tid];       a1 += row[tid + 256];
    a2 += row[tid + 512]; a3 += row[tid + 768];
  }
  atomicAdd(&qsum[b * HS_DIM + tid], a0);
  atomicAdd(&qsum[b * HS_DIM + tid + 256], a1);
  atomicAdd(&qsum[b * HS_DIM + tid + 512], a2);
  atomicAdd(&qsum[b * HS_DIM + tid + 768], a3);
}

// ---------------------------------------------------------------- h = relu(mean(q) @ Wp1 + bp1)
__global__ __launch_bounds__(256) void mlp_h_k(const float* __restrict__ qsum,
                                               const float* __restrict__ Wp1,
                                               const float* __restrict__ bp1,
                                               float* __restrict__ hbuf) {
  __shared__ float red[4][64];
  int b = blockIdx.x >> 3;
  int j0 = (blockIdx.x & 7) * 64;
  int tid = threadIdx.x;
  int j = j0 + (tid & 63), seg = tid >> 6;
  float partial = 0.f;
  for (int i = seg * 256; i < seg * 256 + 256; i++)
    partial += qsum[b * HS_DIM + i] * Wp1[(size_t)i * 512 + j];
  red[seg][tid & 63] = partial;
  __syncthreads();
  if (seg == 0) {
    float s = red[0][tid] + red[1][tid] + red[2][tid] + red[3][tid];
    s = s * (1.0f / 2048.0f) + bp1[j];
    hbuf[b * 512 + j] = fmaxf(s, 0.f);
  }
}

// ---------------------------------------------------------------- pattern softmax + per-(b,h) scale
__global__ __launch_bounds__(256) void patsel_k(const float* __restrict__ hbuf,
                                                const float* __restrict__ Wp2,
                                                const float* __restrict__ bp2,
                                                const float* __restrict__ patterns,
                                                float* __restrict__ patout) {
  __shared__ float logits[16];
  __shared__ float pw[2][8];
  int tid = threadIdx.x;
  int g = tid >> 4, t = tid & 15;
  int b = g >> 3, p = g & 7;
  float partial = 0.f;
  for (int i = t; i < 512; i += 16) partial += hbuf[b * 512 + i] * Wp2[i * 8 + p];
  partial += __shfl_xor(partial, 1, 64);
  partial += __shfl_xor(partial, 2, 64);
  partial += __shfl_xor(partial, 4, 64);
  partial += __shfl_xor(partial, 8, 64);
  if (t == 0) logits[g] = partial + bp2[p];
  __syncthreads();
  if (tid < 2) {
    float mx = -INFINITY;
    for (int i = 0; i < 8; i++) mx = fmaxf(mx, logits[tid * 8 + i]);
    float s = 0.f;
    for (int i = 0; i < 8; i++) { float e = __expf(logits[tid * 8 + i] - mx); pw[tid][i] = e; s += e; }
    float inv = 1.f / s;
    for (int i = 0; i < 8; i++) pw[tid][i] *= inv;
  }
  __syncthreads();
  if (tid < 32) {
    int b2 = tid >> 4, hh = tid & 15;
    float acc = 0.f;
    for (int i = 0; i < 8; i++) acc += pw[b2][i] * patterns[i * 16 + hh];
    patout[b2 * 16 + hh] = acc;
  }
}

// ---------------------------------------------------------------- fused f32 -> bf16 convert for q,k,v
// grid 6144: blockIdx>>11 selects input; 8 elems/thread.
__global__ __launch_bounds__(256) void conv3_bf16_k(const float* __restrict__ q,
                                                    const float* __restrict__ k,
                                                    const float* __restrict__ v,
                                                    unsigned short* __restrict__ out) {
  int which = blockIdx.x >> 11;
  const float* in = (which == 0) ? q : (which == 1) ? k : v;
  size_t idx = (size_t)(blockIdx.x & 2047) * 256 + threadIdx.x;
  const float4* p = (const float4*)in + idx * 2;
  float4 a = p[0], b = p[1];
  uint4 r;
  r.x = (unsigned)f2bf(a.x) | ((unsigned)f2bf(a.y) << 16);
  r.y = (unsigned)f2bf(a.z) | ((unsigned)f2bf(a.w) << 16);
  r.z = (unsigned)f2bf(b.x) | ((unsigned)f2bf(b.y) << 16);
  r.w = (unsigned)f2bf(b.z) | ((unsigned)f2bf(b.w) << 16);
  ((uint4*)(out + (size_t)which * 4194304))[idx] = r;
}

// ---------------------------------------------------------------- W [k][n] f32 -> Wt [n][k] bf16
__global__ __launch_bounds__(256) void transpose_wt_k(
    const float* __restrict__ W0, const float* __restrict__ W1,
    const float* __restrict__ W2, const float* __restrict__ W3,
    unsigned short* __restrict__ T0, unsigned short* __restrict__ T1,
    unsigned short* __restrict__ T2, unsigned short* __restrict__ T3) {
  const float* W = (blockIdx.z == 0) ? W0 : (blockIdx.z == 1) ? W1 : (blockIdx.z == 2) ? W2 : W3;
  unsigned short* Wt = (blockIdx.z == 0) ? T0 : (blockIdx.z == 1) ? T1 : (blockIdx.z == 2) ? T2 : T3;
  __shared__ unsigned short T[64][78];
  int tid = threadIdx.x;
  int r = tid >> 2, c0 = (tid & 3) * 16;
  int k0 = blockIdx.x * 64, n0 = blockIdx.y * 64;
  const float* src = W + (size_t)(k0 + r) * HS_DIM + n0 + c0;
#pragma unroll
  for (int q4 = 0; q4 < 4; q4++) {
    float4 v = ((const float4*)src)[q4];
    T[c0 + q4 * 4 + 0][r] = f2bf(v.x);
    T[c0 + q4 * 4 + 1][r] = f2bf(v.y);
    T[c0 + q4 * 4 + 2][r] = f2bf(v.z);
    T[c0 + q4 * 4 + 3][r] = f2bf(v.w);
  }
  __syncthreads();
  unsigned short* d = Wt + (size_t)(n0 + r) * HS_DIM + k0 + c0;
  unsigned int pk[8];
#pragma unroll
  for (int i = 0; i < 8; i++)
    pk[i] = (unsigned)T[r][c0 + 2 * i] | ((unsigned)T[r][c0 + 2 * i + 1] << 16);
  uint4 o0, o1;
  o0.x = pk[0]; o0.y = pk[1]; o0.z = pk[2]; o0.w = pk[3];
  o1.x = pk[4]; o1.y = pk[5]; o1.z = pk[6]; o1.w = pk[7];
  ((uint4*)d)[0] = o0;
  ((uint4*)d)[1] = o1;
}

// ---------------------------------------------------------------- bf16 GEMM: out = A @ Wt^T + bias
// grid (32,8,NZ): z selects {A matrix, weight, bias, dst}. 768 blocks for QKV = 3 blocks/CU.
// OUT_MODE 0: bf16 into [b][h][s][d] with 16B-chunk XOR swizzle (chunk' = chunk ^ (s&7));
// OUT_MODE 1: f32 [m][n].
template <int OUT_MODE>
__global__ __launch_bounds__(512, 2) void gemm_bf(const unsigned short* __restrict__ A_all,
                                                  const unsigned short* __restrict__ Wt_all,
                                                  const float* __restrict__ b0,
                                                  const float* __restrict__ b1,
                                                  const float* __restrict__ b2,
                                                  void* __restrict__ dst_all) {
  __shared__ __align__(16) unsigned short Al[128 * 32];
  __shared__ __align__(16) unsigned short Bl[128 * 32];
  const int z = blockIdx.z;
  const unsigned short* A = A_all + (size_t)z * 4194304;
  const unsigned short* Bt = Wt_all + (size_t)z * 1048576;
  const float* bias = (z == 0) ? b0 : (z == 1) ? b1 : b2;

  const int tid = threadIdx.x;
  const int w = tid >> 6, lane = tid & 63, quad = lane >> 4, l16 = lane & 15;
  const int wm = w >> 2, wn = w & 3;
  const int m0 = blockIdx.x * 128, n0 = blockIdx.y * 128;

  const int r_s = tid >> 2, kb_s = (tid & 3) * 8;
  const unsigned short* Ag = A + (size_t)(m0 + r_s) * HS_DIM + kb_s;
  const unsigned short* Bg = Bt + (size_t)(n0 + r_s) * HS_DIM + kb_s;
  unsigned short* Al_b = &Al[w * 512];
  unsigned short* Bl_b = &Bl[w * 512];

  floatx4 cd[4][2];
#pragma unroll
  for (int mi = 0; mi < 4; mi++)
#pragma unroll
    for (int ni = 0; ni < 2; ni++) cd[mi][ni] = (floatx4){0.f, 0.f, 0.f, 0.f};

  for (int kt = 0; kt < HS_DIM; kt += 32) {
    __syncthreads();
    gload_lds16(Ag + kt, Al_b);
    gload_lds16(Bg + kt, Bl_b);
    __syncthreads();
    short8 af[4], bf2[2];
#pragma unroll
    for (int mi = 0; mi < 4; mi++)
      af[mi] = *(const short8*)&Al[(wm * 64 + mi * 16 + l16) * 32 + quad * 8];
#pragma unroll
    for (int ni = 0; ni < 2; ni++)
      bf2[ni] = *(const short8*)&Bl[(wn * 32 + ni * 16 + l16) * 32 + quad * 8];
#pragma unroll
    for (int mi = 0; mi < 4; mi++)
#pragma unroll
      for (int ni = 0; ni < 2; ni++) cd[mi][ni] = mfma_bf16(af[mi], bf2[ni], cd[mi][ni]);
  }

#pragma unroll
  for (int ni = 0; ni < 2; ni++) {
    int n = n0 + wn * 32 + ni * 16 + l16;
    float bv = bias[n];
#pragma unroll
    for (int mi = 0; mi < 4; mi++)
#pragma unroll
      for (int jj = 0; jj < 4; jj++) {
        int m = m0 + wm * 64 + mi * 16 + quad * 4 + jj;
        float val = cd[mi][ni][jj] + bv;
        if (OUT_MODE == 0) {
          int bb = m >> 11, s = m & 2047, hh = n >> 6, d = n & 63;
          int sd = (((d >> 3) ^ (s & 7)) << 3) | (d & 7);   // 16B-chunk swizzle
          ((unsigned short*)dst_all + (size_t)z * 4194304)
              [(((size_t)(bb * NHEAD + hh)) * S_LEN + s) * HD_DIM + sd] = f2bf(val);
        } else {
          ((float*)dst_all)[(size_t)m * HS_DIM + n] = val;
        }
      }
  }
}

// ---------------------------------------------------------------- fused attention v3.2
// Q/K/V in global are 16B-chunk XOR-swizzled (chunk' = chunk ^ (row&7)) so that
// global_load_lds (linear dest, PER-LANE source) + unpadded LDS tiles give conflict-free
// ds_read_b128. Phase 1: 128-row K tiles, LDS dbuf, 1 barrier/tile. Phase 2: 64-col
// tiles, K dbuf via gload_lds + Vt dbuf via T14 reg staging, f32 wl -> full-line
// NONTEMPORAL stores (536 MB stream bypasses L2, preserving K/V residency).
__global__ __launch_bounds__(256, 3) void attn_fused(const unsigned short* __restrict__ Q,
                                                     const unsigned short* __restrict__ K,
                                                     const unsigned short* __restrict__ V,
                                                     const unsigned long long* __restrict__ mpack,
                                                     const float* __restrict__ pat,
                                                     float* __restrict__ attn_out,
                                                     unsigned short* __restrict__ ctx) {
  struct P1 { unsigned short Kl[2][128][64]; };                       // 32 KiB
  struct P2 {
    unsigned short Kl[2][64][64];                                     // 16 KiB
    unsigned short Vt[2][64][64];                                     // 16 KiB [buf][d][k'] swizzled V^T
    float wl[4][16][68];                                              // 17 KiB per-wave P tile
  };
  union SMemU { P1 p1; P2 p2; };
  __shared__ __align__(16) SMemU sm;

  const int tid = threadIdx.x;
  const int w = tid >> 6, lane = tid & 63, quad = lane >> 4, l16 = lane & 15;
  // bijective XCD chunk swizzle: 4 heads' K/V per XCD L2
  const int lin = blockIdx.x + (blockIdx.y << 5);
  const int nid = ((lin & 7) << 7) + (lin >> 3);
  const int bh = nid >> 5;
  const int q0 = (nid & 31) << 6;
  const int b = bh >> 4, h = bh & 15;

  const unsigned short* Qb = Q + ((size_t)bh * S_LEN + q0) * HD_DIM;
  const unsigned short* Kb = K + (size_t)bh * S_LEN * HD_DIM;
  const unsigned short* Vb = V + (size_t)bh * S_LEN * HD_DIM;
  const float scl = 0.125f * pat[bh];

  // fragment chunk offsets under the global swizzle (frag rows have row&7 == l16&7)
  const int key_q = l16 & 7;
  const int cs0 = (quad ^ key_q) << 3;          // k 0..31
  const int cs1 = ((quad + 4) ^ key_q) << 3;    // k 32..63

  const int qrow_w = w * 16 + l16;
  const short8 aq0 = *(const short8*)(Qb + (size_t)qrow_w * HD_DIM + cs0);
  const short8 aq1 = *(const short8*)(Qb + (size_t)qrow_w * HD_DIM + cs1);

  const int qrow_base = q0 + w * 16 + quad * 4;
  const unsigned long long* mrow = mpack + ((size_t)b * S_LEN + qrow_base) * 32;

  float m_i[4], l_i[4];
#pragma unroll
  for (int jj = 0; jj < 4; jj++) { m_i[jj] = -INFINITY; l_i[jj] = 0.f; }

  // per-lane source offset for linear 1KiB wave copies (8 contiguous 128B rows)
  const int lofs = lane * 8;   // shorts

  auto stage_k1 = [&](int jt, int buf) {
    const unsigned short* kg = Kb + ((size_t)jt * 128 + w * 32) * HD_DIM + lofs;
#pragma unroll
    for (int t = 0; t < 4; t++)
      gload_lds16(kg + t * 8 * HD_DIM, &sm.p1.Kl[buf][w * 32 + t * 8][0]);
  };

  // ---------------- phase 1: per-row max & sum(exp) ----------------
  stage_k1(0, 0);
  __syncthreads();
  for (int jt = 0; jt < 16; ++jt) {
    const int buf = jt & 1;
    if (jt < 15) stage_k1(jt + 1, buf ^ 1);
    floatx4 c[8];
#pragma unroll
    for (int nt = 0; nt < 8; nt++) {
      const unsigned short* kr = &sm.p1.Kl[buf][nt * 16 + l16][0];
      floatx4 acc = (floatx4){0.f, 0.f, 0.f, 0.f};
      acc = mfma_bf16(aq0, *(const short8*)(kr + cs0), acc);
      acc = mfma_bf16(aq1, *(const short8*)(kr + cs1), acc);
      c[nt] = acc;
    }
#pragma unroll
    for (int jj = 0; jj < 4; jj++) {
      unsigned long long pk0 = mrow[jj * 32 + jt * 2];
      unsigned long long pk1 = mrow[jj * 32 + jt * 2 + 1];
      float sv[8], tmax = -INFINITY;
#pragma unroll
      for (int nt = 0; nt < 8; nt++) {
        int col = nt * 16 + l16;
        unsigned long long bits = (nt < 4) ? pk0 : pk1;
        float s = ((bits >> (col & 63)) & 1ull) ? c[nt][jj] * scl : -1e9f;
        sv[nt] = s; tmax = fmaxf(tmax, s);
      }
      tmax = bfly_max16(tmax);
      float newm = fmaxf(m_i[jj], tmax);
      float ps = 0.f;
#pragma unroll
      for (int nt = 0; nt < 8; nt++) ps += __expf(sv[nt] - newm);
      ps = bfly_sum16(ps);
      l_i[jj] = l_i[jj] * __expf(m_i[jj] - newm) + ps;
      m_i[jj] = newm;
    }
    __syncthreads();
  }
  float inv_l[4];
#pragma unroll
  for (int jj = 0; jj < 4; jj++) inv_l[jj] = 1.f / l_i[jj];

  // ---------------- phase 2: weights out + PV ----------------
  floatx4 o[4];
#pragma unroll
  for (int dt = 0; dt < 4; dt++) o[dt] = (floatx4){0.f, 0.f, 0.f, 0.f};

  const int vrow = tid >> 2;     // tile kpos 0..63
  const int vc = tid & 3;        // stored-chunk pair (vc, vc+4)
  const int kr7 = vrow & 7, krh = vrow >> 3;
  uint4 vreg0, vreg1;

  auto stage_k2 = [&](int j, int buf) {
    const unsigned short* kg = Kb + ((size_t)j * 64 + w * 16) * HD_DIM + lofs;
    gload_lds16(kg, &sm.p2.Kl[buf][w * 16][0]);
    gload_lds16(kg + 8 * HD_DIM, &sm.p2.Kl[buf][w * 16 + 8][0]);
  };
  auto load_v = [&](int j) {
    const unsigned short* vg = Vb + ((size_t)j * 64 + vrow) * HD_DIM;
    vreg0 = *(const uint4*)(vg + vc * 8);
    vreg1 = *(const uint4*)(vg + (vc + 4) * 8);
  };
  auto scatter_v = [&](int buf) {
    union U8 { uint4 v; unsigned short u[8]; } U0, U1;
    U0.v = vreg0; U1.v = vreg1;
    const int dc0 = vc ^ kr7, dc1 = (vc + 4) ^ kr7;    // actual d-chunks
#pragma unroll
    for (int i = 0; i < 8; i++) {
      int kd0 = i ^ dc0;                                // key(d) = (d&7)^(d>>3)
      sm.p2.Vt[buf][(dc0 << 3) + i][((krh ^ kd0) << 3) + kr7] = U0.u[i];
      int kd1 = i ^ dc1;
      sm.p2.Vt[buf][(dc1 << 3) + i][((krh ^ kd1) << 3) + kr7] = U1.u[i];
    }
  };

  stage_k2(0, 0);
  load_v(0);
  scatter_v(0);
  __syncthreads();

  float* arow = attn_out + (size_t)bh * S_LEN * S_LEN + (size_t)q0 * S_LEN;
  for (int j = 0; j < 32; ++j) {
    const int buf = j & 1;
    // T14 issue-early: next K tile (gload_lds) + next V tile (regs)
    if (j < 31) { stage_k2(j + 1, buf ^ 1); load_v(j + 1); }

    unsigned long long pk[4];
#pragma unroll
    for (int jj = 0; jj < 4; jj++) pk[jj] = mrow[jj * 32 + j];

    // QK^T from Kl[buf] + softmax finish -> wl (f32)
#pragma unroll
    for (int nt = 0; nt < 4; nt++) {
      const unsigned short* kr = &sm.p2.Kl[buf][nt * 16 + l16][0];
      floatx4 acc = (floatx4){0.f, 0.f, 0.f, 0.f};
      acc = mfma_bf16(aq0, *(const short8*)(kr + cs0), acc);
      acc = mfma_bf16(aq1, *(const short8*)(kr + cs1), acc);
      const int col = nt * 16 + l16;
#pragma unroll
      for (int jj = 0; jj < 4; jj++) {
        float s = ((pk[jj] >> col) & 1ull) ? acc[jj] * scl : -1e9f;
        sm.p2.wl[w][quad * 4 + jj][col] = __expf(s - m_i[jj]) * inv_l[jj];
      }
    }

    // weight store: 256B contiguous per row segment, nontemporal (bypass L2)
#pragma unroll
    for (int p = 0; p < 4; p++) {
      int r = p * 4 + quad;
      floatx4 wv4 = *(const floatx4*)&sm.p2.wl[w][r][l16 * 4];
      __builtin_nontemporal_store(
          wv4, (floatx4*)(arow + (size_t)(w * 16 + r) * S_LEN + j * 64 + l16 * 4));
    }

    // PV: A from wl (f32 -> bf16), B from Vt[buf]
#pragma unroll
    for (int ks = 0; ks < 2; ks++) {
      float4 wa0 = *(const float4*)&sm.p2.wl[w][l16][ks * 32 + quad * 8];
      float4 wa1 = *(const float4*)&sm.p2.wl[w][l16][ks * 32 + quad * 8 + 4];
      short8 pa;
      pa[0] = (short)f2bf(wa0.x); pa[1] = (short)f2bf(wa0.y);
      pa[2] = (short)f2bf(wa0.z); pa[3] = (short)f2bf(wa0.w);
      pa[4] = (short)f2bf(wa1.x); pa[5] = (short)f2bf(wa1.y);
      pa[6] = (short)f2bf(wa1.z); pa[7] = (short)f2bf(wa1.w);
#pragma unroll
      for (int dt = 0; dt < 4; dt++) {
        int d = dt * 16 + l16;
        int kd = (d & 7) ^ (d >> 3);
        o[dt] = mfma_bf16(pa, *(const short8*)&sm.p2.Vt[buf][d][((ks * 4 + quad) ^ kd) << 3],
                          o[dt]);
      }
    }

    // T14 write-late: publish next V tile
    if (j < 31) scatter_v(buf ^ 1);
    __syncthreads();
  }

  // ctx bf16 [b][s][h*64+d] (standard layout for the output GEMM)
#pragma unroll
  for (int dt = 0; dt < 4; dt++)
#pragma unroll
    for (int jj = 0; jj < 4; jj++)
      ctx[((size_t)b * S_LEN + qrow_base + jj) * HS_DIM + h * HD_DIM + dt * 16 + l16] =
          f2bf(o[dt][jj]);
}

// ---------------------------------------------------------------- launch
extern "C" void kernel_launch(void* const* d_in, const int* in_sizes, int n_in,
                              void* d_out, int out_size, void* d_ws, size_t ws_size,
                              hipStream_t stream) {
  const float* query = (const float*)d_in[0];
  const float* key   = (const float*)d_in[1];
  const float* value = (const float*)d_in[2];
  const int*   amask = (const int*)d_in[3];
  const float* Wq = (const float*)d_in[4];
  const float* bq = (const float*)d_in[5];
  const float* Wk = (const float*)d_in[6];
  const float* bk = (const float*)d_in[7];
  const float* Wv = (const float*)d_in[8];
  const float* bv = (const float*)d_in[9];
  const float* Wo = (const float*)d_in[10];
  const float* bo = (const float*)d_in[11];
  const float* Wp1 = (const float*)d_in[12];
  const float* bp1 = (const float*)d_in[13];
  const float* Wp2 = (const float*)d_in[14];
  const float* bp2 = (const float*)d_in[15];
  const float* patterns = (const float*)d_in[16];

  float* out = (float*)d_out;                           // [2,2048,1024] f32
  float* attn = out + (size_t)NBATCH * S_LEN * HS_DIM;  // [2,16,2048,2048] f32
  // 24 MiB bf16 scratch inside the attn-weights region (fully overwritten by attn_fused
  // afterwards): offset 384 MiB into the 536 MiB region.
  unsigned short* cqkv = (unsigned short*)(attn + (size_t)100663296);

  char* ws = (char*)d_ws;
  unsigned short* cb  = (unsigned short*)(ws + 0);         // 8 MiB ctx bf16
  unsigned short* Wqt = (unsigned short*)(ws + 8388608);   // 2 MiB each (Wqt,Wkt,Wvt,Wot)
  unsigned short* Wkt = (unsigned short*)(ws + 10485760);
  unsigned short* Wvt = (unsigned short*)(ws + 12582912);
  unsigned short* Wot = (unsigned short*)(ws + 14680064);
  unsigned short* Qw  = (unsigned short*)(ws + 16777216);  // 8 MiB each (swizzled), contiguous
  unsigned short* Kw  = (unsigned short*)(ws + 25165824);
  unsigned short* Vw  = (unsigned short*)(ws + 33554432);
  unsigned long long* mpack = (unsigned long long*)(ws + 41943040);  // 1 MiB
  float* qsum = (float*)(ws + 42991616);                   // 8 KiB
  float* hbuf = (float*)(ws + 42999808);                   // 4 KiB
  float* patb = (float*)(ws + 43003904);                   // 128 B

  hipMemsetAsync(qsum, 0, 8192, stream);

  pack_mask_k<<<dim3(32768), dim3(256), 0, stream>>>(amask, mpack);
  qsum_k<<<dim3(128), dim3(256), 0, stream>>>(query, qsum);
  mlp_h_k<<<dim3(16), dim3(256), 0, stream>>>(qsum, Wp1, bp1, hbuf);
  patsel_k<<<dim3(1), dim3(256), 0, stream>>>(hbuf, Wp2, bp2, patterns, patb);

  transpose_wt_k<<<dim3(16, 16, 4), dim3(256), 0, stream>>>(Wq, Wk, Wv, Wo,
                                                            Wqt, Wkt, Wvt, Wot);

  conv3_bf16_k<<<dim3(6144), dim3(256), 0, stream>>>(query, key, value, cqkv);
  gemm_bf<0><<<dim3(32, 8, 3), dim3(512), 0, stream>>>(cqkv, Wqt, bq, bk, bv, (void*)Qw);

  attn_fused<<<dim3(32, 32), dim3(256), 0, stream>>>(Qw, Kw, Vw, mpack, patb, attn, cb);

  gemm_bf<1><<<dim3(32, 8, 1), dim3(512), 0, stream>>>(cb, Wot, bo, bo, bo, (void*)out);
}